// Round 5
// baseline (220.077 us; speedup 1.0000x reference)
//
#include <hip/hip_runtime.h>
#include <hip/hip_bf16.h>
#include <stdint.h>

// GAT layer: N=8192, F_IN=256, F_OUT=64, two branches (adj_in/adj_out), shared 'a'.

#define NN 8192
#define ALPHA 0.2f
#define L2E 1.44269504088896f
#define AL2E 0.288539008177792f   // 0.2 * log2(e)

typedef _Float16 f16;
typedef _Float16 f16x2 __attribute__((ext_vector_type(2)));
typedef _Float16 f16x4 __attribute__((ext_vector_type(4)));
typedef _Float16 f16x8 __attribute__((ext_vector_type(8)));
typedef float f32x4 __attribute__((ext_vector_type(4)));
typedef unsigned int u32;

// workspace layout (bytes). E1/E2 overlay WT (dead after k2). BITS overlays PACC
// (PACC only used in the small-ws fallback path).
#define WS_WT    0u         // f16 [128][256]
#define WS_E1    0u         // f16 [2][8192]
#define WS_E2    32768u     // f16 [2][8192]
#define WS_HT    65536u     // f16 [2][1024][64][8] blocked: HTB[b][j>>3][c][j&7]
#define WS_SRC   2162688u   // f32 [2][8192]
#define WS_DST   2228224u   // f32 [2][8192]
#define WS_DMAX  2293760u   // f32 [2]
#define WS_PACC  2294016u   // f32 [2][8192][64]  (fallback only)
#define WS_BITS  2294016u   // u32 [2][8192][256] bit-packed adj (16.8 MB)
#define WS_BIG_NEED 19071232ull

static __device__ __forceinline__ void gload16(const void* g, void* l) {
    __builtin_amdgcn_global_load_lds(
        (const __attribute__((address_space(1))) void*)g,
        (__attribute__((address_space(3))) void*)l, 16, 0, 0);
}

// ---------------- kernel 1: WT[c][k] = W[k][c] as f16 ----------------
__global__ __launch_bounds__(256) void k1_wt(const float* __restrict__ Win,
                                             const float* __restrict__ Wout,
                                             f16* __restrict__ WT) {
    int c = blockIdx.x;
    int k = threadIdx.x;
    const float* W = (c < 64) ? Win : Wout;
    int cc = c & 63;
    WT[(size_t)c * 256 + k] = (f16)W[(size_t)k * 64 + cc];
}

// ---------------- kernel 2: h = x@W (MFMA), emit blocked HTB f16 + src/dst ----------------
__global__ __launch_bounds__(64) void k2_h(const float* __restrict__ x,
                                           const f16* __restrict__ WT,
                                           const float* __restrict__ a,
                                           f16* __restrict__ HT,
                                           float* __restrict__ srcw,
                                           float* __restrict__ dstw) {
    int l = threadIdx.x;
    int l15 = l & 15, lhi = l >> 4;
    int row0 = blockIdx.x * 16;

    f32x4 acc[8];
#pragma unroll
    for (int n = 0; n < 8; n++) { acc[n][0]=0.f; acc[n][1]=0.f; acc[n][2]=0.f; acc[n][3]=0.f; }

#pragma unroll
    for (int kc = 0; kc < 8; kc++) {
        int k = kc * 32 + lhi * 8;
        const float* xp = x + (size_t)(row0 + l15) * 256 + k;
        float4 xa = *(const float4*)xp;
        float4 xb = *(const float4*)(xp + 4);
        f16x8 af;
        af[0]=(f16)xa.x; af[1]=(f16)xa.y; af[2]=(f16)xa.z; af[3]=(f16)xa.w;
        af[4]=(f16)xb.x; af[5]=(f16)xb.y; af[6]=(f16)xb.z; af[7]=(f16)xb.w;
#pragma unroll
        for (int n = 0; n < 8; n++) {
            f16x8 bf = *(const f16x8*)(WT + (size_t)(16 * n + l15) * 256 + k);
            acc[n] = __builtin_amdgcn_mfma_f32_16x16x32_f16(af, bf, acc[n], 0, 0, 0);
        }
    }

    float as4[4], ad4[4];
#pragma unroll
    for (int nn = 0; nn < 4; nn++) {
        as4[nn] = a[16 * nn + l15];
        ad4[nn] = a[64 + 16 * nn + l15];
    }

    float s_in[4] = {0,0,0,0}, d_in[4] = {0,0,0,0};
    float s_out[4] = {0,0,0,0}, d_out[4] = {0,0,0,0};

#pragma unroll
    for (int n = 0; n < 8; n++) {
        int b = n >> 2;
        int ci = 16 * (n & 3) + l15;
        int jj = row0 + 4 * lhi;
        f16x4 hv;
#pragma unroll
        for (int q = 0; q < 4; q++) hv[q] = (f16)acc[n][q];
        *(f16x4*)(HT + (size_t)b * 524288 + (size_t)(jj >> 3) * 512 + (size_t)ci * 8 + (jj & 7)) = hv;
#pragma unroll
        for (int q = 0; q < 4; q++) {
            float v = acc[n][q];
            if (b == 0) { s_in[q]  += v * as4[n & 3]; d_in[q]  += v * ad4[n & 3]; }
            else        { s_out[q] += v * as4[n & 3]; d_out[q] += v * ad4[n & 3]; }
        }
    }

#pragma unroll
    for (int q = 0; q < 4; q++) {
#pragma unroll
        for (int m = 1; m < 16; m <<= 1) {
            s_in[q]  += __shfl_xor(s_in[q],  m, 64);
            d_in[q]  += __shfl_xor(d_in[q],  m, 64);
            s_out[q] += __shfl_xor(s_out[q], m, 64);
            d_out[q] += __shfl_xor(d_out[q], m, 64);
        }
    }
    if (l15 == 0) {
        int row = row0 + 4 * lhi;
#pragma unroll
        for (int q = 0; q < 4; q++) {
            srcw[row + q]        = s_in[q];
            srcw[8192 + row + q] = s_out[q];
            dstw[row + q]        = d_in[q];
            dstw[8192 + row + q] = d_out[q];
        }
    }
}

// ---------------- kernel 3: per-branch max of dst ----------------
__global__ __launch_bounds__(256) void k3_dmax(const float* __restrict__ dstw,
                                               float* __restrict__ dmax) {
    __shared__ float red[2][4];
    int t = threadIdx.x;
    int l = t & 63, w = t >> 6;
    for (int b = 0; b < 2; b++) {
        float v = -1e30f;
        for (int i = t; i < 8192; i += 256) v = fmaxf(v, dstw[b * 8192 + i]);
#pragma unroll
        for (int m = 1; m < 64; m <<= 1) v = fmaxf(v, __shfl_xor(v, m, 64));
        if (l == 0) red[b][w] = v;
    }
    __syncthreads();
    if (t == 0) dmax[0] = fmaxf(fmaxf(red[0][0], red[0][1]), fmaxf(red[0][2], red[0][3]));
    if (t == 1) dmax[1] = fmaxf(fmaxf(red[1][0], red[1][1]), fmaxf(red[1][2], red[1][3]));
}

// ---------------- kernel 3b: E tables, f16, normalized by dmax ----------------
__global__ __launch_bounds__(256) void k3b_e(const float* __restrict__ dstw,
                                             const float* __restrict__ dmax,
                                             f16* __restrict__ E1,
                                             f16* __restrict__ E2) {
    int i = blockIdx.x * 256 + threadIdx.x;
    int b = i >> 13;
    float d = dstw[i] - dmax[b];
    E1[i] = (f16)exp2f(d * L2E);
    E2[i] = (f16)exp2f(d * AL2E);
}

// ---------------- kernel P: bit-pack adjacency (the pure roofline stream) ----------------
// Each wave-iteration reads 1KB dense (256 ints of one row) and emits 8 bitmask
// words via a 3-step shfl_xor nibble butterfly. bitsg[b][row][w], bit j of word
// w = adj[row][w*32+j].
__global__ __launch_bounds__(256) void k_pack(const int* __restrict__ adj_in,
                                              const int* __restrict__ adj_out,
                                              u32* __restrict__ bits) {
    int t = threadIdx.x;
    int l = t & 63, wv = t >> 6;
    int nwaves = gridDim.x * 4;
    for (int c = blockIdx.x * 4 + wv; c < 524288; c += nwaves) {
        int branch = c >> 18;            // 8192*32 chunks per branch = 2^18
        int row = (c >> 5) & 8191;
        int ch = c & 31;                 // 256-int chunk within row
        const int* src = (branch ? adj_out : adj_in) + (size_t)row * 8192 + ch * 256 + l * 4;
        int4 a = *(const int4*)src;
        u32 nib = (u32)(a.x > 0) | ((u32)(a.y > 0) << 1) | ((u32)(a.z > 0) << 2) | ((u32)(a.w > 0) << 3);
        u32 v = nib << ((l & 7) * 4);
        v |= (u32)__shfl_xor((int)v, 1, 64);
        v |= (u32)__shfl_xor((int)v, 2, 64);
        v |= (u32)__shfl_xor((int)v, 4, 64);
        if ((l & 7) == 0)
            bits[(size_t)branch * 2097152 + (size_t)row * 256 + ch * 8 + (l >> 3)] = v;
    }
}

// ---------------- kernel 4 (bits path): fused masked-softmax-attn, both branches ----------------
// Block = 512 threads (8 waves), 32 rows, BOTH branches; wave wv: branch=wv>>2,
// j-quarter q=wv&3. Bitmask rows (64KB) staged into LDS once; main loop is
// barrier-free: bits from LDS + E/HT from L2 + MFMA. Epilogue merges 4 q-waves
// per branch, normalizes, combines branches, applies ELU, writes out directly.
__global__ __launch_bounds__(512, 2) void k4_bits(const u32* __restrict__ bitsg,
                                                  const f16* __restrict__ HT,
                                                  const float* __restrict__ srcw,
                                                  const float* __restrict__ dmaxp,
                                                  const f16* __restrict__ E1g,
                                                  const f16* __restrict__ E2g,
                                                  float* __restrict__ out) {
    __shared__ __align__(16) char lds[66560];  // bits [2][32][1040B]; reused: accL 64KB + dnp 1KB

    int t = threadIdx.x;
    int row0 = blockIdx.x * 32;
    int l = t & 63, wv = t >> 6;
    int B = wv >> 2, q = wv & 3;
    int l15 = l & 15, lhi = l >> 4;
    int lhi8 = lhi * 8;

    // stage bitmask rows: bitsL[branch][r][260 u32 padded to 1040B]
#pragma unroll
    for (int p = 0; p < 8; p++) {
        int idx = p * 512 + t;            // 0..4095 16B chunks (2 br x 32 r x 64)
        int bb = idx >> 11;
        int r  = (idx >> 6) & 31;
        int c16 = idx & 63;
        uint4 v = *(const uint4*)(bitsg + (size_t)bb * 2097152 + (size_t)(row0 + r) * 256 + c16 * 4);
        *(uint4*)(lds + bb * 33280 + r * 1040 + c16 * 16) = v;
    }

    // per-row constants for the two row-halves this wave covers
    const float* srcb = srcw + B * NN;
    float dmaxv = dmaxp[B];
    f16x8 k1v0, k2v0, k1v1, k2v1;
    {
        float srcv = srcb[row0 + l15];
        float md = srcv + dmaxv;
        float mlog = fmaxf(md, ALPHA * md) * L2E;
        f16 k1 = (f16)exp2f(md * L2E - mlog);
        f16 k2 = (f16)exp2f(ALPHA * md * L2E - mlog);
#pragma unroll
        for (int i = 0; i < 8; i++) { k1v0[i] = k1; k2v0[i] = k2; }
    }
    {
        float srcv = srcb[row0 + 16 + l15];
        float md = srcv + dmaxv;
        float mlog = fmaxf(md, ALPHA * md) * L2E;
        f16 k1 = (f16)exp2f(md * L2E - mlog);
        f16 k2 = (f16)exp2f(ALPHA * md * L2E - mlog);
#pragma unroll
        for (int i = 0; i < 8; i++) { k1v1[i] = k1; k2v1[i] = k2; }
    }

    const f16* htg = HT + (size_t)B * (64 * NN);
    const f16* e1b = E1g + B * NN;
    const f16* e2b = E2g + B * NN;
    const u32* bl0 = (const u32*)(lds + B * 33280 + l15 * 1040);
    const u32* bl1 = (const u32*)(lds + B * 33280 + (l15 + 16) * 1040);

    f32x4 acc0[4], acc1[4];
#pragma unroll
    for (int n = 0; n < 4; n++) {
        acc0[n][0]=0.f; acc0[n][1]=0.f; acc0[n][2]=0.f; acc0[n][3]=0.f;
        acc1[n][0]=0.f; acc1[n][1]=0.f; acc1[n][2]=0.f; acc1[n][3]=0.f;
    }
    float dn0 = 0.f, dn1 = 0.f;
    f16x2 one2; one2[0] = (f16)1.f; one2[1] = (f16)1.f;

    __syncthreads();

    for (int tile = 0; tile < 32; tile++) {
#pragma unroll
        for (int ss = 0; ss < 2; ss++) {
            int widx = tile * 8 + q * 2 + ss;
            u32 bw0 = bl0[widx];
            u32 bw1 = bl1[widx];
            int jg = tile * 256 + q * 64 + ss * 32 + lhi8;

            f16x8 e1v = *(const f16x8*)(e1b + jg);
            f16x8 e2v = *(const f16x8*)(e2b + jg);

            u32 by0 = (bw0 >> lhi8) & 0xFFu;
            u32 by1 = (bw1 >> lhi8) & 0xFFu;
            union { u32 u[4]; f16x8 h; } m0, m1;
#pragma unroll
            for (int p = 0; p < 4; p++) {
                m0.u[p] = (((by0 >> (2 * p)) & 1u) | (((by0 >> (2 * p + 1)) & 1u) << 16)) * 0x3C00u;
                m1.u[p] = (((by1 >> (2 * p)) & 1u) | (((by1 >> (2 * p + 1)) & 1u) << 16)) * 0x3C00u;
            }
            f16x8 w0 = __builtin_elementwise_max(e1v * k1v0, e2v * k2v0) * m0.h;
            f16x8 w1 = __builtin_elementwise_max(e1v * k1v1, e2v * k2v1) * m1.h;

            union { f16x8 h; f16x2 pr[4]; } u0, u1;
            u0.h = w0; u1.h = w1;
#if __has_builtin(__builtin_amdgcn_fdot2)
#pragma unroll
            for (int p = 0; p < 4; p++) {
                dn0 = __builtin_amdgcn_fdot2(u0.pr[p], one2, dn0, false);
                dn1 = __builtin_amdgcn_fdot2(u1.pr[p], one2, dn1, false);
            }
#else
#pragma unroll
            for (int e = 0; e < 8; e++) { dn0 += (float)w0[e]; dn1 += (float)w1[e]; }
#endif

            const f16* hb = htg + (size_t)(jg >> 3) * 512 + l15 * 8;
            f16x8 b0 = *(const f16x8*)(hb);
            f16x8 b1 = *(const f16x8*)(hb + 128);
            f16x8 b2 = *(const f16x8*)(hb + 256);
            f16x8 b3 = *(const f16x8*)(hb + 384);
            acc0[0] = __builtin_amdgcn_mfma_f32_16x16x32_f16(w0, b0, acc0[0], 0, 0, 0);
            acc0[1] = __builtin_amdgcn_mfma_f32_16x16x32_f16(w0, b1, acc0[1], 0, 0, 0);
            acc0[2] = __builtin_amdgcn_mfma_f32_16x16x32_f16(w0, b2, acc0[2], 0, 0, 0);
            acc0[3] = __builtin_amdgcn_mfma_f32_16x16x32_f16(w0, b3, acc0[3], 0, 0, 0);
            acc1[0] = __builtin_amdgcn_mfma_f32_16x16x32_f16(w1, b0, acc1[0], 0, 0, 0);
            acc1[1] = __builtin_amdgcn_mfma_f32_16x16x32_f16(w1, b1, acc1[1], 0, 0, 0);
            acc1[2] = __builtin_amdgcn_mfma_f32_16x16x32_f16(w1, b2, acc1[2], 0, 0, 0);
            acc1[3] = __builtin_amdgcn_mfma_f32_16x16x32_f16(w1, b3, acc1[3], 0, 0, 0);
        }
    }

    // reduce dn over lhi groups (rows are per-l15)
    dn0 += __shfl_xor(dn0, 16, 64); dn0 += __shfl_xor(dn0, 32, 64);
    dn1 += __shfl_xor(dn1, 16, 64); dn1 += __shfl_xor(dn1, 32, 64);

    __syncthreads();   // done with bits; reuse LDS
    float* accL = (float*)lds;             // [8][32][64]
    float* dnp  = (float*)(lds + 65536);   // [8][32]
    if (lhi == 0) { dnp[wv * 32 + l15] = dn0; dnp[wv * 32 + 16 + l15] = dn1; }
#pragma unroll
    for (int n = 0; n < 4; n++)
#pragma unroll
        for (int qr = 0; qr < 4; qr++) {
            accL[wv * 2048 + (4 * lhi + qr) * 64 + 16 * n + l15]        = acc0[n][qr];
            accL[wv * 2048 + (16 + 4 * lhi + qr) * 64 + 16 * n + l15]   = acc1[n][qr];
        }
    __syncthreads();

    int r = t >> 4;              // 0..31
    int c4 = (t & 15) * 4;
    float inv0 = 1.0f / (dnp[r] + dnp[32 + r] + dnp[64 + r] + dnp[96 + r]);
    float inv1 = 1.0f / (dnp[128 + r] + dnp[160 + r] + dnp[192 + r] + dnp[224 + r]);
    float4 o;
#pragma unroll
    for (int cc = 0; cc < 4; cc++) {
        int idx = r * 64 + c4 + cc;
        float v0 = (accL[idx] + accL[2048 + idx] + accL[4096 + idx] + accL[6144 + idx]) * inv0;
        float v1 = (accL[8192 + idx] + accL[10240 + idx] + accL[12288 + idx] + accL[14336 + idx]) * inv1;
        float h = 0.5f * (v0 + v1);
        ((float*)&o)[cc] = (h > 0.f) ? h : (exp2f(h * L2E) - 1.f);
    }
    *(float4*)(out + (size_t)(row0 + r) * 64 + c4) = o;
}

// ---------------- fallback (small ws): round-4 k4 + combine ----------------
__global__ __launch_bounds__(256, 4) void k4_main(const int* __restrict__ adj_in,
                                                  const int* __restrict__ adj_out,
                                                  const f16* __restrict__ HT,
                                                  const float* __restrict__ srcw,
                                                  const float* __restrict__ dmaxp,
                                                  const f16* __restrict__ E1g,
                                                  const f16* __restrict__ E2g,
                                                  float* __restrict__ pacc) {
    __shared__ __align__(16) char lds[33024];

    int t = threadIdx.x;
    int branch = blockIdx.x & 1;
    int row0 = (blockIdx.x >> 1) * 16;
    const int* adj = (branch ? adj_out : adj_in) + (size_t)row0 * NN;
    const f16* htg = HT + (size_t)branch * (64 * NN);
    const f16* e1b = E1g + branch * NN;
    const f16* e2b = E2g + branch * NN;

    int l = t & 63, wv = t >> 6;
    int l15 = l & 15, lhi = l >> 4;
    int sw = l15 & 7;

    float srcv = srcw[branch * NN + row0 + l15];
    float dmaxv = dmaxp[branch];
    float md = srcv + dmaxv;
    float mlog = fmaxf(md, ALPHA * md) * L2E;
    f16 k1h = (f16)exp2f(md * L2E - mlog);
    f16 k2h = (f16)exp2f(ALPHA * md * L2E - mlog);
    f16x8 k1v, k2v;
#pragma unroll
    for (int i = 0; i < 8; i++) { k1v[i] = k1h; k2v[i] = k2h; }

    f32x4 acc[4];
#pragma unroll
    for (int n = 0; n < 4; n++) { acc[n][0]=0.f; acc[n][1]=0.f; acc[n][2]=0.f; acc[n][3]=0.f; }
    float dn = 0.f;
    f16x2 one2; one2[0] = (f16)1.f; one2[1] = (f16)1.f;

    auto stage = [&](int tile, int buf) {
        const int* base = adj + tile * 256;
#pragma unroll
        for (int i = 0; i < 4; i++) {
            int r = wv * 4 + i;
            const int* src = base + (size_t)r * NN + ((l ^ (r & 7)) << 2);
            gload16(src, lds + buf * 16384 + r * 1024);
        }
    };

    stage(0, 0);
    asm volatile("s_waitcnt vmcnt(0)" ::: "memory");
    __builtin_amdgcn_s_barrier();

    for (int tile = 0; tile < 32; tile++) {
        int buf = tile & 1;
        if (tile < 31) stage(tile + 1, buf ^ 1);

#pragma unroll
        for (int ss = 0; ss < 2; ss++) {
            int jloc = wv * 64 + ss * 32;
            int qb = (jloc >> 2) + 2 * lhi;
            const char* rowp = lds + buf * 16384 + l15 * 1024;
            int4 a0 = *(const int4*)(rowp + (((qb    ) ^ sw) << 4));
            int4 a1 = *(const int4*)(rowp + (((qb + 1) ^ sw) << 4));

            int jg = tile * 256 + jloc + lhi * 8;
            f16x8 e1v = *(const f16x8*)(e1b + jg);
            f16x8 e2v = *(const f16x8*)(e2b + jg);
            f16x8 w = __builtin_elementwise_max(e1v * k1v, e2v * k2v);

            union { u32 u[4]; f16x8 h; } mu;
            mu.u[0] = (u32)(a0.x + (a0.y << 16)) * 0x3C00u;
            mu.u[1] = (u32)(a0.z + (a0.w << 16)) * 0x3C00u;
            mu.u[2] = (u32)(a1.x + (a1.y << 16)) * 0x3C00u;
            mu.u[3] = (u32)(a1.z + (a1.w << 16)) * 0x3C00u;
            w = w * mu.h;

            union { f16x8 h; f16x2 p[4]; } wu; wu.h = w;
#if __has_builtin(__builtin_amdgcn_fdot2)
            dn = __builtin_amdgcn_fdot2(wu.p[0], one2, dn, false);
            dn = __builtin_amdgcn_fdot2(wu.p[1], one2, dn, false);
            dn = __builtin_amdgcn_fdot2(wu.p[2], one2, dn, false);
            dn = __builtin_amdgcn_fdot2(wu.p[3], one2, dn, false);
#else
#pragma unroll
            for (int e = 0; e < 8; e++) dn += (float)w[e];
#endif

            const f16* hb = htg + (size_t)(jg >> 3) * 512 + l15 * 8;
            f16x8 b0 = *(const f16x8*)(hb);
            f16x8 b1 = *(const f16x8*)(hb + 128);
            f16x8 b2 = *(const f16x8*)(hb + 256);
            f16x8 b3 = *(const f16x8*)(hb + 384);
            acc[0] = __builtin_amdgcn_mfma_f32_16x16x32_f16(w, b0, acc[0], 0, 0, 0);
            acc[1] = __builtin_amdgcn_mfma_f32_16x16x32_f16(w, b1, acc[1], 0, 0, 0);
            acc[2] = __builtin_amdgcn_mfma_f32_16x16x32_f16(w, b2, acc[2], 0, 0, 0);
            acc[3] = __builtin_amdgcn_mfma_f32_16x16x32_f16(w, b3, acc[3], 0, 0, 0);
        }

        asm volatile("s_waitcnt vmcnt(0)" ::: "memory");
        __builtin_amdgcn_s_barrier();
    }

    dn += __shfl_xor(dn, 16, 64);
    dn += __shfl_xor(dn, 32, 64);

    float* accL = (float*)lds;
    float* dnp  = (float*)(lds + 16384);
    float* dnr  = (float*)(lds + 16384 + 256);
    if (lhi == 0) dnp[wv * 16 + l15] = dn;
#pragma unroll
    for (int n = 0; n < 4; n++)
#pragma unroll
        for (int q = 0; q < 4; q++)
            accL[wv * 1024 + (4 * lhi + q) * 64 + 16 * n + l15] = acc[n][q];
    __syncthreads();

    if (t < 16) dnr[t] = 1.0f / (dnp[t] + dnp[16 + t] + dnp[32 + t] + dnp[48 + t]);
    __syncthreads();

    int r = t >> 4;
    int c4 = (t & 15) * 4;
    float inv = dnr[r];
    float4 o;
    o.x = (accL[r*64+c4+0] + accL[1024+r*64+c4+0] + accL[2048+r*64+c4+0] + accL[3072+r*64+c4+0]) * inv;
    o.y = (accL[r*64+c4+1] + accL[1024+r*64+c4+1] + accL[2048+r*64+c4+1] + accL[3072+r*64+c4+1]) * inv;
    o.z = (accL[r*64+c4+2] + accL[1024+r*64+c4+2] + accL[2048+r*64+c4+2] + accL[3072+r*64+c4+2]) * inv;
    o.w = (accL[r*64+c4+3] + accL[1024+r*64+c4+3] + accL[2048+r*64+c4+3] + accL[3072+r*64+c4+3]) * inv;
    *(float4*)(pacc + (size_t)branch * 524288 + (size_t)(row0 + r) * 64 + c4) = o;
}

__global__ __launch_bounds__(256) void k5_combine(const float* __restrict__ pacc,
                                                  float* __restrict__ out) {
    size_t idx = (size_t)blockIdx.x * 256 + threadIdx.x;
    float4 p0 = *(const float4*)(pacc + idx * 4);
    float4 p1 = *(const float4*)(pacc + 524288 + idx * 4);
    float4 o;
    float v;
    v = 0.5f * (p0.x + p1.x); o.x = (v > 0.f) ? v : (exp2f(v * L2E) - 1.f);
    v = 0.5f * (p0.y + p1.y); o.y = (v > 0.f) ? v : (exp2f(v * L2E) - 1.f);
    v = 0.5f * (p0.z + p1.z); o.z = (v > 0.f) ? v : (exp2f(v * L2E) - 1.f);
    v = 0.5f * (p0.w + p1.w); o.w = (v > 0.f) ? v : (exp2f(v * L2E) - 1.f);
    *(float4*)(out + idx * 4) = o;
}

extern "C" void kernel_launch(void* const* d_in, const int* in_sizes, int n_in,
                              void* d_out, int out_size, void* d_ws, size_t ws_size,
                              hipStream_t stream) {
    const float* x       = (const float*)d_in[0];
    const int*   adj_in  = (const int*)d_in[1];
    const int*   adj_out = (const int*)d_in[2];
    const float* W_in    = (const float*)d_in[3];
    const float* W_out   = (const float*)d_in[4];
    const float* a       = (const float*)d_in[5];
    float* out = (float*)d_out;

    char* ws = (char*)d_ws;
    f16*   WT   = (f16*)(ws + WS_WT);
    f16*   E1   = (f16*)(ws + WS_E1);
    f16*   E2   = (f16*)(ws + WS_E2);
    f16*   HT   = (f16*)(ws + WS_HT);
    float* srcw = (float*)(ws + WS_SRC);
    float* dstw = (float*)(ws + WS_DST);
    float* dmax = (float*)(ws + WS_DMAX);

    hipLaunchKernelGGL(k1_wt,   dim3(128), dim3(256), 0, stream, W_in, W_out, WT);
    hipLaunchKernelGGL(k2_h,    dim3(512), dim3(64),  0, stream, x, WT, a, HT, srcw, dstw);
    hipLaunchKernelGGL(k3_dmax, dim3(1),   dim3(256), 0, stream, dstw, dmax);
    hipLaunchKernelGGL(k3b_e,   dim3(64),  dim3(256), 0, stream, dstw, dmax, E1, E2);

    if (ws_size >= WS_BIG_NEED) {
        u32* bits = (u32*)(ws + WS_BITS);
        hipLaunchKernelGGL(k_pack,  dim3(2048), dim3(256), 0, stream, adj_in, adj_out, bits);
        hipLaunchKernelGGL(k4_bits, dim3(256),  dim3(512), 0, stream, bits, HT, srcw, dmax, E1, E2, out);
    } else {
        float* pacc = (float*)(ws + WS_PACC);
        hipLaunchKernelGGL(k4_main,   dim3(1024), dim3(256), 0, stream, adj_in, adj_out, HT, srcw, dmax, E1, E2, pacc);
        hipLaunchKernelGGL(k5_combine,dim3(512),  dim3(256), 0, stream, pacc, out);
    }
}

// Round 6
// 143.452 us; speedup vs baseline: 1.5341x; 1.5341x over previous
//
#include <hip/hip_runtime.h>
#include <hip/hip_bf16.h>
#include <stdint.h>

// GAT layer: N=8192, F_IN=256, F_OUT=64, two branches (adj_in/adj_out), shared 'a'.

#define NN 8192
#define ALPHA 0.2f
#define L2E 1.44269504088896f
#define AL2E 0.288539008177792f   // 0.2 * log2(e)

typedef _Float16 f16;
typedef _Float16 f16x2 __attribute__((ext_vector_type(2)));
typedef _Float16 f16x4 __attribute__((ext_vector_type(4)));
typedef _Float16 f16x8 __attribute__((ext_vector_type(8)));
typedef float f32x4 __attribute__((ext_vector_type(4)));
typedef unsigned int u32;

// workspace layout (bytes). E1/E2 overlay WT (dead after k2).
#define WS_WT    0u         // f16 [128][256]
#define WS_E1    0u         // f16 [2][8192]
#define WS_E2    32768u     // f16 [2][8192]
#define WS_HT    65536u     // f16 [2][1024][64][8] blocked: HTB[b][j>>3][c][j&7]
#define WS_SRC   2162688u   // f32 [2][8192]
#define WS_DST   2228224u   // f32 [2][8192]
#define WS_DMAX  2293760u   // f32 [2]
#define WS_PACC  2294016u   // f32 [2][8192][64]

static __device__ __forceinline__ void gload16(const void* g, void* l) {
    __builtin_amdgcn_global_load_lds(
        (const __attribute__((address_space(1))) void*)g,
        (__attribute__((address_space(3))) void*)l, 16, 0, 0);
}

// ---------------- kernel 1: WT[c][k] = W[k][c] as f16 ----------------
__global__ __launch_bounds__(256) void k1_wt(const float* __restrict__ Win,
                                             const float* __restrict__ Wout,
                                             f16* __restrict__ WT) {
    int c = blockIdx.x;
    int k = threadIdx.x;
    const float* W = (c < 64) ? Win : Wout;
    int cc = c & 63;
    WT[(size_t)c * 256 + k] = (f16)W[(size_t)k * 64 + cc];
}

// ---------------- kernel 2: h = x@W (MFMA), emit blocked HTB f16 + src/dst ----------------
__global__ __launch_bounds__(64) void k2_h(const float* __restrict__ x,
                                           const f16* __restrict__ WT,
                                           const float* __restrict__ a,
                                           f16* __restrict__ HT,
                                           float* __restrict__ srcw,
                                           float* __restrict__ dstw) {
    int l = threadIdx.x;
    int l15 = l & 15, lhi = l >> 4;
    int row0 = blockIdx.x * 16;

    f32x4 acc[8];
#pragma unroll
    for (int n = 0; n < 8; n++) { acc[n][0]=0.f; acc[n][1]=0.f; acc[n][2]=0.f; acc[n][3]=0.f; }

#pragma unroll
    for (int kc = 0; kc < 8; kc++) {
        int k = kc * 32 + lhi * 8;
        const float* xp = x + (size_t)(row0 + l15) * 256 + k;
        float4 xa = *(const float4*)xp;
        float4 xb = *(const float4*)(xp + 4);
        f16x8 af;
        af[0]=(f16)xa.x; af[1]=(f16)xa.y; af[2]=(f16)xa.z; af[3]=(f16)xa.w;
        af[4]=(f16)xb.x; af[5]=(f16)xb.y; af[6]=(f16)xb.z; af[7]=(f16)xb.w;
#pragma unroll
        for (int n = 0; n < 8; n++) {
            f16x8 bf = *(const f16x8*)(WT + (size_t)(16 * n + l15) * 256 + k);
            acc[n] = __builtin_amdgcn_mfma_f32_16x16x32_f16(af, bf, acc[n], 0, 0, 0);
        }
    }

    float as4[4], ad4[4];
#pragma unroll
    for (int nn = 0; nn < 4; nn++) {
        as4[nn] = a[16 * nn + l15];
        ad4[nn] = a[64 + 16 * nn + l15];
    }

    float s_in[4] = {0,0,0,0}, d_in[4] = {0,0,0,0};
    float s_out[4] = {0,0,0,0}, d_out[4] = {0,0,0,0};

#pragma unroll
    for (int n = 0; n < 8; n++) {
        int b = n >> 2;
        int ci = 16 * (n & 3) + l15;
        int jj = row0 + 4 * lhi;
        f16x4 hv;
#pragma unroll
        for (int q = 0; q < 4; q++) hv[q] = (f16)acc[n][q];
        *(f16x4*)(HT + (size_t)b * 524288 + (size_t)(jj >> 3) * 512 + (size_t)ci * 8 + (jj & 7)) = hv;
#pragma unroll
        for (int q = 0; q < 4; q++) {
            float v = acc[n][q];
            if (b == 0) { s_in[q]  += v * as4[n & 3]; d_in[q]  += v * ad4[n & 3]; }
            else        { s_out[q] += v * as4[n & 3]; d_out[q] += v * ad4[n & 3]; }
        }
    }

#pragma unroll
    for (int q = 0; q < 4; q++) {
#pragma unroll
        for (int m = 1; m < 16; m <<= 1) {
            s_in[q]  += __shfl_xor(s_in[q],  m, 64);
            d_in[q]  += __shfl_xor(d_in[q],  m, 64);
            s_out[q] += __shfl_xor(s_out[q], m, 64);
            d_out[q] += __shfl_xor(d_out[q], m, 64);
        }
    }
    if (l15 == 0) {
        int row = row0 + 4 * lhi;
#pragma unroll
        for (int q = 0; q < 4; q++) {
            srcw[row + q]        = s_in[q];
            srcw[8192 + row + q] = s_out[q];
            dstw[row + q]        = d_in[q];
            dstw[8192 + row + q] = d_out[q];
        }
    }
}

// ---------------- kernel 3: per-branch max of dst ----------------
__global__ __launch_bounds__(256) void k3_dmax(const float* __restrict__ dstw,
                                               float* __restrict__ dmax) {
    __shared__ float red[2][4];
    int t = threadIdx.x;
    int l = t & 63, w = t >> 6;
    for (int b = 0; b < 2; b++) {
        float v = -1e30f;
        for (int i = t; i < 8192; i += 256) v = fmaxf(v, dstw[b * 8192 + i]);
#pragma unroll
        for (int m = 1; m < 64; m <<= 1) v = fmaxf(v, __shfl_xor(v, m, 64));
        if (l == 0) red[b][w] = v;
    }
    __syncthreads();
    if (t == 0) dmax[0] = fmaxf(fmaxf(red[0][0], red[0][1]), fmaxf(red[0][2], red[0][3]));
    if (t == 1) dmax[1] = fmaxf(fmaxf(red[1][0], red[1][1]), fmaxf(red[1][2], red[1][3]));
}

// ---------------- kernel 3b: E tables, f16, normalized by dmax ----------------
__global__ __launch_bounds__(256) void k3b_e(const float* __restrict__ dstw,
                                             const float* __restrict__ dmax,
                                             f16* __restrict__ E1,
                                             f16* __restrict__ E2) {
    int i = blockIdx.x * 256 + threadIdx.x;
    int b = i >> 13;
    float d = dstw[i] - dmax[b];
    E1[i] = (f16)exp2f(d * L2E);
    E2[i] = (f16)exp2f(d * AL2E);
}

// ---------------- kernel 4: fused masked-softmax-attention, deep DMA pipeline ----------------
// Block = 4 waves, 16 rows, one branch. j tiled by 256. adj staged via
// coalesced global_load_lds into a 4-deep LDS ring (64 KB), stage issued 2
// tiles ahead. Raw s_barrier (no drain); the only vmem waits in the loop are
// the compiler's waits for the L2-resident E/HT register loads, which leave
// the newest adj stage in flight (counted-vmcnt pattern). 2 blocks/CU.
__global__ __launch_bounds__(256, 2) void k4_main(const int* __restrict__ adj_in,
                                                  const int* __restrict__ adj_out,
                                                  const f16* __restrict__ HT,
                                                  const float* __restrict__ srcw,
                                                  const float* __restrict__ dmaxp,
                                                  const f16* __restrict__ E1g,
                                                  const f16* __restrict__ E2g,
                                                  float* __restrict__ pacc) {
    __shared__ __align__(16) char lds[66048];   // 4 x 16KB adj ring; epilogue reuses

    int t = threadIdx.x;
    int branch = blockIdx.x & 1;
    int row0 = (blockIdx.x >> 1) * 16;
    const int* adj = (branch ? adj_out : adj_in) + (size_t)row0 * NN;
    const f16* htg = HT + (size_t)branch * (64 * NN);
    const f16* e1b = E1g + branch * NN;
    const f16* e2b = E2g + branch * NN;

    int l = t & 63, wv = t >> 6;
    int l15 = l & 15, lhi = l >> 4;
    int sw = l15 & 7;

    // per-row constants: ev = max(k1*E1[j], k2*E2[j]) = exp2(LR(src+d)*L2E - mlog)
    float srcv = srcw[branch * NN + row0 + l15];
    float dmaxv = dmaxp[branch];
    float md = srcv + dmaxv;
    float mlog = fmaxf(md, ALPHA * md) * L2E;
    f16 k1h = (f16)exp2f(md * L2E - mlog);
    f16 k2h = (f16)exp2f(ALPHA * md * L2E - mlog);
    f16x8 k1v, k2v;
#pragma unroll
    for (int i = 0; i < 8; i++) { k1v[i] = k1h; k2v[i] = k2h; }

    f32x4 acc[4];
#pragma unroll
    for (int n = 0; n < 4; n++) { acc[n][0]=0.f; acc[n][1]=0.f; acc[n][2]=0.f; acc[n][3]=0.f; }
    float dn = 0.f;
    f16x2 one2; one2[0] = (f16)1.f; one2[1] = (f16)1.f;

    auto stage = [&](int tile) {
        int buf = tile & 3;
        const int* base = adj + tile * 256;
#pragma unroll
        for (int i = 0; i < 4; i++) {
            int r = wv * 4 + i;
            const int* src = base + (size_t)r * NN + ((l ^ (r & 7)) << 2);
            gload16(src, lds + buf * 16384 + r * 1024);
        }
    };

    // prologue: stages 0 and 1 in flight; require stage 0 complete only.
    stage(0);
    stage(1);
    asm volatile("s_waitcnt vmcnt(4)");          // stage1's 4 loads may remain
    __builtin_amdgcn_sched_barrier(0);
    __builtin_amdgcn_s_barrier();

    for (int tile = 0; tile < 32; tile++) {
        int buf = tile & 3;
        const char* rowp = lds + buf * 16384 + l15 * 1024;

        // 1) adj for both ss slices from LDS (lgkm-waited by compiler)
        int qb0 = (wv * 64 >> 2) + 2 * lhi;
        int4 a0 = *(const int4*)(rowp + (((qb0    ) ^ sw) << 4));
        int4 a1 = *(const int4*)(rowp + (((qb0 + 1) ^ sw) << 4));
        int qb1 = qb0 + 8;
        int4 a2 = *(const int4*)(rowp + (((qb1    ) ^ sw) << 4));
        int4 a3 = *(const int4*)(rowp + (((qb1 + 1) ^ sw) << 4));

        // 2) E/HT register loads for this tile (L2-resident)
        int jg0 = tile * 256 + wv * 64 + lhi * 8;
        int jg1 = jg0 + 32;
        f16x8 e1v0 = *(const f16x8*)(e1b + jg0);
        f16x8 e2v0 = *(const f16x8*)(e2b + jg0);
        f16x8 e1v1 = *(const f16x8*)(e1b + jg1);
        f16x8 e2v1 = *(const f16x8*)(e2b + jg1);
        const f16* hb0 = htg + (size_t)(jg0 >> 3) * 512 + l15 * 8;
        const f16* hb1 = htg + (size_t)(jg1 >> 3) * 512 + l15 * 8;
        f16x8 b00 = *(const f16x8*)(hb0);
        f16x8 b01 = *(const f16x8*)(hb0 + 128);
        f16x8 b02 = *(const f16x8*)(hb0 + 256);
        f16x8 b03 = *(const f16x8*)(hb0 + 384);
        f16x8 b10 = *(const f16x8*)(hb1);
        f16x8 b11 = *(const f16x8*)(hb1 + 128);
        f16x8 b12 = *(const f16x8*)(hb1 + 256);
        f16x8 b13 = *(const f16x8*)(hb1 + 384);
        __builtin_amdgcn_sched_barrier(0);

        // 3) stage tile+2 (newest vmem ops -> compiler's waits for E/HT leave these in flight)
        if (tile < 30) stage(tile + 2);
        __builtin_amdgcn_sched_barrier(0);

        // 4) masks + weights + MFMA, slice 0
        {
            union { u32 u[4]; f16x8 h; } mu;
            mu.u[0] = (u32)(a0.x + (a0.y << 16)) * 0x3C00u;
            mu.u[1] = (u32)(a0.z + (a0.w << 16)) * 0x3C00u;
            mu.u[2] = (u32)(a1.x + (a1.y << 16)) * 0x3C00u;
            mu.u[3] = (u32)(a1.z + (a1.w << 16)) * 0x3C00u;
            f16x8 w = __builtin_elementwise_max(e1v0 * k1v, e2v0 * k2v) * mu.h;
            union { f16x8 h; f16x2 p[4]; } wu; wu.h = w;
#if __has_builtin(__builtin_amdgcn_fdot2)
            dn = __builtin_amdgcn_fdot2(wu.p[0], one2, dn, false);
            dn = __builtin_amdgcn_fdot2(wu.p[1], one2, dn, false);
            dn = __builtin_amdgcn_fdot2(wu.p[2], one2, dn, false);
            dn = __builtin_amdgcn_fdot2(wu.p[3], one2, dn, false);
#else
#pragma unroll
            for (int e = 0; e < 8; e++) dn += (float)w[e];
#endif
            acc[0] = __builtin_amdgcn_mfma_f32_16x16x32_f16(w, b00, acc[0], 0, 0, 0);
            acc[1] = __builtin_amdgcn_mfma_f32_16x16x32_f16(w, b01, acc[1], 0, 0, 0);
            acc[2] = __builtin_amdgcn_mfma_f32_16x16x32_f16(w, b02, acc[2], 0, 0, 0);
            acc[3] = __builtin_amdgcn_mfma_f32_16x16x32_f16(w, b03, acc[3], 0, 0, 0);
        }
        // 5) slice 1
        {
            union { u32 u[4]; f16x8 h; } mu;
            mu.u[0] = (u32)(a2.x + (a2.y << 16)) * 0x3C00u;
            mu.u[1] = (u32)(a2.z + (a2.w << 16)) * 0x3C00u;
            mu.u[2] = (u32)(a3.x + (a3.y << 16)) * 0x3C00u;
            mu.u[3] = (u32)(a3.z + (a3.w << 16)) * 0x3C00u;
            f16x8 w = __builtin_elementwise_max(e1v1 * k1v, e2v1 * k2v) * mu.h;
            union { f16x8 h; f16x2 p[4]; } wu; wu.h = w;
#if __has_builtin(__builtin_amdgcn_fdot2)
            dn = __builtin_amdgcn_fdot2(wu.p[0], one2, dn, false);
            dn = __builtin_amdgcn_fdot2(wu.p[1], one2, dn, false);
            dn = __builtin_amdgcn_fdot2(wu.p[2], one2, dn, false);
            dn = __builtin_amdgcn_fdot2(wu.p[3], one2, dn, false);
#else
#pragma unroll
            for (int e = 0; e < 8; e++) dn += (float)w[e];
#endif
            acc[0] = __builtin_amdgcn_mfma_f32_16x16x32_f16(w, b10, acc[0], 0, 0, 0);
            acc[1] = __builtin_amdgcn_mfma_f32_16x16x32_f16(w, b11, acc[1], 0, 0, 0);
            acc[2] = __builtin_amdgcn_mfma_f32_16x16x32_f16(w, b12, acc[2], 0, 0, 0);
            acc[3] = __builtin_amdgcn_mfma_f32_16x16x32_f16(w, b13, acc[3], 0, 0, 0);
        }

        // 6) raw barrier: stage(tile+1) already drained by this tile's E/HT waits;
        //    stage(tile+2) intentionally remains in flight across the barrier.
        __builtin_amdgcn_s_barrier();
    }

    // epilogue: reduce dn, merge 4 waves' partials (reuse ring LDS after full drain)
    dn += __shfl_xor(dn, 16, 64);
    dn += __shfl_xor(dn, 32, 64);
    __syncthreads();   // full drain OK here (loop done)

    float* accL = (float*)lds;               // [4][16][64]
    float* dnp  = (float*)(lds + 16384);     // [4][16]
    float* dnr  = (float*)(lds + 16384 + 256);
    if (lhi == 0) dnp[wv * 16 + l15] = dn;
#pragma unroll
    for (int n = 0; n < 4; n++)
#pragma unroll
        for (int q = 0; q < 4; q++)
            accL[wv * 1024 + (4 * lhi + q) * 64 + 16 * n + l15] = acc[n][q];
    __syncthreads();

    if (t < 16) dnr[t] = 1.0f / (dnp[t] + dnp[16 + t] + dnp[32 + t] + dnp[48 + t]);
    __syncthreads();

    int r = t >> 4;
    int c4 = (t & 15) * 4;
    float inv = dnr[r];
    float4 o;
    o.x = (accL[r*64+c4+0] + accL[1024+r*64+c4+0] + accL[2048+r*64+c4+0] + accL[3072+r*64+c4+0]) * inv;
    o.y = (accL[r*64+c4+1] + accL[1024+r*64+c4+1] + accL[2048+r*64+c4+1] + accL[3072+r*64+c4+1]) * inv;
    o.z = (accL[r*64+c4+2] + accL[1024+r*64+c4+2] + accL[2048+r*64+c4+2] + accL[3072+r*64+c4+2]) * inv;
    o.w = (accL[r*64+c4+3] + accL[1024+r*64+c4+3] + accL[2048+r*64+c4+3] + accL[3072+r*64+c4+3]) * inv;
    *(float4*)(pacc + (size_t)branch * 524288 + (size_t)(row0 + r) * 64 + c4) = o;
}

// ---------------- kernel 5: combine branches + ELU ----------------
__global__ __launch_bounds__(256) void k5_combine(const float* __restrict__ pacc,
                                                  float* __restrict__ out) {
    size_t idx = (size_t)blockIdx.x * 256 + threadIdx.x;
    float4 p0 = *(const float4*)(pacc + idx * 4);
    float4 p1 = *(const float4*)(pacc + 524288 + idx * 4);
    float4 o;
    float v;
    v = 0.5f * (p0.x + p1.x); o.x = (v > 0.f) ? v : (exp2f(v * L2E) - 1.f);
    v = 0.5f * (p0.y + p1.y); o.y = (v > 0.f) ? v : (exp2f(v * L2E) - 1.f);
    v = 0.5f * (p0.z + p1.z); o.z = (v > 0.f) ? v : (exp2f(v * L2E) - 1.f);
    v = 0.5f * (p0.w + p1.w); o.w = (v > 0.f) ? v : (exp2f(v * L2E) - 1.f);
    *(float4*)(out + idx * 4) = o;
}

extern "C" void kernel_launch(void* const* d_in, const int* in_sizes, int n_in,
                              void* d_out, int out_size, void* d_ws, size_t ws_size,
                              hipStream_t stream) {
    const float* x       = (const float*)d_in[0];
    const int*   adj_in  = (const int*)d_in[1];
    const int*   adj_out = (const int*)d_in[2];
    const float* W_in    = (const float*)d_in[3];
    const float* W_out   = (const float*)d_in[4];
    const float* a       = (const float*)d_in[5];
    float* out = (float*)d_out;

    char* ws = (char*)d_ws;
    f16*   WT   = (f16*)(ws + WS_WT);
    f16*   E1   = (f16*)(ws + WS_E1);
    f16*   E2   = (f16*)(ws + WS_E2);
    f16*   HT   = (f16*)(ws + WS_HT);
    float* srcw = (float*)(ws + WS_SRC);
    float* dstw = (float*)(ws + WS_DST);
    float* dmax = (float*)(ws + WS_DMAX);
    float* pacc = (float*)(ws + WS_PACC);
    // requires ws_size >= ~6.2 MB

    hipLaunchKernelGGL(k1_wt,     dim3(128),  dim3(256), 0, stream, W_in, W_out, WT);
    hipLaunchKernelGGL(k2_h,      dim3(512),  dim3(64),  0, stream, x, WT, a, HT, srcw, dstw);
    hipLaunchKernelGGL(k3_dmax,   dim3(1),    dim3(256), 0, stream, dstw, dmax);
    hipLaunchKernelGGL(k3b_e,     dim3(64),   dim3(256), 0, stream, dstw, dmax, E1, E2);
    hipLaunchKernelGGL(k4_main,   dim3(1024), dim3(256), 0, stream, adj_in, adj_out, HT, srcw, dmax, E1, E2, pacc);
    hipLaunchKernelGGL(k5_combine,dim3(512),  dim3(256), 0, stream, pacc, out);
}